// Round 4
// baseline (130.175 us; speedup 1.0000x reference)
//
#include <hip/hip_runtime.h>
#include <hip/hip_bf16.h>
#include <stdint.h>
#include <math.h>

#define NROWS 8192
#define DIM   256          // elements per row; fp8 -> 256 B per row
#define BJ    256          // j rows per block (A operand)
#define BI    128          // i rows per block (B operand)
#define NJT   (NROWS/BJ)   // 32
#define NIT   (NROWS/BI)   // 64

typedef __attribute__((ext_vector_type(4))) int   int4v;
typedef __attribute__((ext_vector_type(8))) int   int8v;
typedef __attribute__((ext_vector_type(4))) float floatx4;

#define SCALE_1_16 0x7B7B7B7B     // E8M0 123 = 2^-4 in every byte
#define L2E10      14.4269504088896f   // 10 * log2(e)

// ------------- Kernel 1: row-normalize fp32 -> fp8 e4m3 (x16), one wave/row -------------
__global__ __launch_bounds__(256) void normalize_kernel(const float* __restrict__ emb,
                                                        uint32_t* __restrict__ e8)
{
    int row  = blockIdx.x * 4 + (threadIdx.x >> 6);
    int lane = threadIdx.x & 63;
    const float4* rowp = (const float4*)(emb + (size_t)row * DIM);
    float4 v = rowp[lane];
    float ss = v.x*v.x + v.y*v.y + v.z*v.z + v.w*v.w;
    #pragma unroll
    for (int off = 32; off > 0; off >>= 1)
        ss += __shfl_xor(ss, off, 64);
    // store e * 16 in e4m3; the MFMA scales (2^-4 per operand) remove the 2^8
    float inv = 16.0f / fmaxf(sqrtf(ss), 1e-8f);
    int r = __builtin_amdgcn_cvt_pk_fp8_f32(v.x * inv, v.y * inv, 0, false);
    r     = __builtin_amdgcn_cvt_pk_fp8_f32(v.z * inv, v.w * inv, r, true);
    e8[(size_t)row * (DIM / 4) + lane] = (uint32_t)r;
}

// ------------- Kernel 2: 256j x 128i tile, MX-fp8 K=128 MFMA, no LDS, no barriers -------
// C[row=j][col=i]: lane owns fixed i per tc (i = wc+tc*16+m), j's live in registers.
// All operand fragments loaded straight from L2 (whole fp8 matrix = 2 MB, L2-resident).
template<bool DIAG>
__device__ __forceinline__ void epilogue_accum(const floatx4 acc[8][4],
                                               const int* __restrict__ tgt,
                                               int bi, int bj, int wr, int wc,
                                               int quad, int m,
                                               const int tiv[4], const int ic[4],
                                               float ps[4], float ts[4])
{
    const int jb = bj * BJ + wr + (quad << 2);
    #pragma unroll
    for (int tj = 0; tj < 8; ++tj) {
        const int jg = jb + tj * 16;
        const int4v t4 = *(const int4v*)(tgt + jg);   // 4 consecutive j-targets, 16B aligned
        #pragma unroll
        for (int tc = 0; tc < 4; ++tc) {
            const int tivc = tiv[tc];
            #pragma unroll
            for (int r = 0; r < 4; ++r) {
                float v = exp2f(fmaf(L2E10, acc[tj][tc][r], -L2E10));
                if (DIAG) {
                    if (jg + r == ic[tc]) v = 0.f;    // exclude diagonal
                }
                ts[tc] += v;
                ps[tc] += (t4[r] == tivc) ? v : 0.f;
            }
        }
    }
}

__global__ __launch_bounds__(256, 2) void tile_kernel(const uint8_t* __restrict__ e8,
                                                      const int* __restrict__ tgt,
                                                      float* __restrict__ pps,
                                                      float* __restrict__ pts)
{
    const int bi   = blockIdx.x;
    const int bj   = blockIdx.y;
    const int tid  = threadIdx.x;
    const int wave = tid >> 6;
    const int lane = tid & 63;
    const int quad = lane >> 4;
    const int m    = lane & 15;

    const int wr = (wave >> 1) * 128;  // wave j base within block
    const int wc = (wave & 1) * 64;    // wave i base within block

    floatx4 acc[8][4];
    #pragma unroll
    for (int a = 0; a < 8; ++a)
        #pragma unroll
        for (int b = 0; b < 4; ++b)
            acc[a][b] = (floatx4){0.f, 0.f, 0.f, 0.f};

    // fragment base pointers: lane (m, quad) reads row (base + t*16 + m),
    // k-bytes [kc*128 + quad*32, +32) -- the f8f6f4 A/B operand layout (validated R3)
    const uint8_t* pA = e8 + (size_t)(bj * BJ + wr + m) * 256 + quad * 32;
    const uint8_t* pB = e8 + (size_t)(bi * BI + wc + m) * 256 + quad * 32;

    #pragma unroll
    for (int kc = 0; kc < 2; ++kc) {
        int8v bfr[4];
        #pragma unroll
        for (int tc = 0; tc < 4; ++tc)
            bfr[tc] = *(const int8v*)(pB + tc * 16 * 256 + kc * 128);
        int8v af[8];
        #pragma unroll
        for (int tj = 0; tj < 8; ++tj)
            af[tj] = *(const int8v*)(pA + tj * 16 * 256 + kc * 128);

        #pragma unroll
        for (int tj = 0; tj < 8; ++tj)
            #pragma unroll
            for (int tc = 0; tc < 4; ++tc)
                acc[tj][tc] = __builtin_amdgcn_mfma_scale_f32_16x16x128_f8f6f4(
                    af[tj], bfr[tc], acc[tj][tc], 0, 0,
                    0, SCALE_1_16, 0, SCALE_1_16);
    }

    // ---- epilogue: exp(sim-10); total + positive sums per fixed i ----
    int tiv[4], ic[4];
    #pragma unroll
    for (int tc = 0; tc < 4; ++tc) {
        ic[tc]  = bi * BI + wc + tc * 16 + m;
        tiv[tc] = tgt[ic[tc]];
    }

    float ps[4] = {0.f, 0.f, 0.f, 0.f};
    float ts[4] = {0.f, 0.f, 0.f, 0.f};

    if ((bi >> 1) == bj)   // block-uniform: only 64/2048 blocks touch the diagonal
        epilogue_accum<true >(acc, tgt, bi, bj, wr, wc, quad, m, tiv, ic, ps, ts);
    else
        epilogue_accum<false>(acc, tgt, bi, bj, wr, wc, quad, m, tiv, ic, ps, ts);

    // quad-reduction: lanes m, m+16, m+32, m+48 hold disjoint j's for the same i
    #pragma unroll
    for (int tc = 0; tc < 4; ++tc) {
        ps[tc] += __shfl_xor(ps[tc], 16, 64);
        ps[tc] += __shfl_xor(ps[tc], 32, 64);
        ts[tc] += __shfl_xor(ts[tc], 16, 64);
        ts[tc] += __shfl_xor(ts[tc], 32, 64);
    }
    if (quad == 0) {
        const size_t base = (size_t)(bj * 2 + (wave >> 1)) * NROWS;
        #pragma unroll
        for (int tc = 0; tc < 4; ++tc) {
            pps[base + ic[tc]] = ps[tc];
            pts[base + ic[tc]] = ts[tc];
        }
    }
}

// ------------- Kernel 3: per-row log-diff + global sum -------------
__global__ __launch_bounds__(256) void finalize_kernel(const float* __restrict__ pps,
                                                       const float* __restrict__ pts,
                                                       float* __restrict__ out)
{
    const int i = blockIdx.x * 256 + threadIdx.x;
    float sp = 0.f, st = 0.f;
    #pragma unroll 8
    for (int t = 0; t < NJT * 2; ++t) {
        sp += pps[(size_t)t * NROWS + i];
        st += pts[(size_t)t * NROWS + i];
    }
    float ns = st - sp;                 // negatives = total - positives (diag excluded in both)
    float loss = logf(ns) - logf(sp);   // fixed +10 shifts cancel
    #pragma unroll
    for (int off = 32; off > 0; off >>= 1)
        loss += __shfl_xor(loss, off, 64);
    __shared__ float w4[4];
    if ((threadIdx.x & 63) == 0) w4[threadIdx.x >> 6] = loss;
    __syncthreads();
    if (threadIdx.x == 0)
        atomicAdd(out, w4[0] + w4[1] + w4[2] + w4[3]);
}

extern "C" void kernel_launch(void* const* d_in, const int* in_sizes, int n_in,
                              void* d_out, int out_size, void* d_ws, size_t ws_size,
                              hipStream_t stream)
{
    (void)in_sizes; (void)n_in; (void)out_size; (void)ws_size;
    const float* emb = (const float*)d_in[0];
    const int*   tgt = (const int*)d_in[1];
    float*       out = (float*)d_out;

    uint32_t* e8  = (uint32_t*)d_ws;                                  // 2 MB fp8 rows
    float*    pps = (float*)((char*)d_ws + (size_t)NROWS * 256);      // 2 MB
    float*    pts = pps + (size_t)NJT * 2 * NROWS;                    // 2 MB

    hipMemsetAsync(d_out, 0, sizeof(float), stream);

    normalize_kernel<<<NROWS / 4, 256, 0, stream>>>(emb, e8);

    dim3 grid(NIT, NJT);
    tile_kernel<<<grid, 256, 0, stream>>>((const uint8_t*)e8, tgt, pps, pts);

    finalize_kernel<<<NROWS / 256, 256, 0, stream>>>(pps, pts, out);
}

// Round 5
// 107.876 us; speedup vs baseline: 1.2067x; 1.2067x over previous
//
#include <hip/hip_runtime.h>
#include <hip/hip_bf16.h>
#include <stdint.h>
#include <math.h>

#define NROWS 8192
#define DIM   256          // elements per row; fp8 -> 256 B per row
#define BJ    128          // j rows per block (A operand)
#define BI    128          // i rows per block (B operand)
#define KCB   128          // K-bytes staged per chunk
#define NKC   2            // 256 B / 128 B
#define NJT   (NROWS/BJ)   // 64
#define NIT   (NROWS/BI)   // 64
#define NPART (NJT*2)      // 128 partial rows (2 wave-rows per bj)

typedef __attribute__((ext_vector_type(4))) int   int4v;
typedef __attribute__((ext_vector_type(8))) int   int8v;
typedef __attribute__((ext_vector_type(4))) float floatx4;

typedef const __attribute__((address_space(1))) uint32_t gas_u32;
typedef __attribute__((address_space(3))) uint32_t las_u32;

#define SCALE_1_16 0x7B7B7B7B          // E8M0 123 = 2^-4 in every byte
#define L2E10      14.4269504088896f   // 10 * log2(e)

__device__ __forceinline__ void gload_lds16(const void* g, void* l) {
    // LDS dest = wave-uniform base + lane*16 ; global src per-lane
    __builtin_amdgcn_global_load_lds((gas_u32*)(uintptr_t)g,
                                     (las_u32*)(uintptr_t)l, 16, 0, 0);
}

// ------------- Kernel 1: row-normalize fp32 -> fp8 e4m3 (x16); also zero d_out -------------
__global__ __launch_bounds__(256) void normalize_kernel(const float* __restrict__ emb,
                                                        uint32_t* __restrict__ e8,
                                                        float* __restrict__ out)
{
    if (blockIdx.x == 0 && threadIdx.x == 0) *out = 0.f;   // replaces memset dispatch
    int row  = blockIdx.x * 4 + (threadIdx.x >> 6);
    int lane = threadIdx.x & 63;
    const float4* rowp = (const float4*)(emb + (size_t)row * DIM);
    float4 v = rowp[lane];
    float ss = v.x*v.x + v.y*v.y + v.z*v.z + v.w*v.w;
    #pragma unroll
    for (int off = 32; off > 0; off >>= 1)
        ss += __shfl_xor(ss, off, 64);
    // store e * 16 in e4m3; MFMA scales (2^-4 per operand) remove the 2^8
    float inv = 16.0f / fmaxf(sqrtf(ss), 1e-8f);
    int r = __builtin_amdgcn_cvt_pk_fp8_f32(v.x * inv, v.y * inv, 0, false);
    r     = __builtin_amdgcn_cvt_pk_fp8_f32(v.z * inv, v.w * inv, r, true);
    e8[(size_t)row * (DIM / 4) + lane] = (uint32_t)r;
}

// ------------- Kernel 2: 128j x 128i tile, MX-fp8 K=128 MFMA, LDS-staged -------------
// C[row=j][col=i]: lane owns fixed i per tc (i = wc+tc*16+m), j's accumulate in register.
template<bool DIAG>
__device__ __forceinline__ void epilogue_accum(const floatx4 acc[4][4],
                                               const int* __restrict__ tgt,
                                               int jb, const int tiv[4], const int ic[4],
                                               float ps[4], float ts[4])
{
    #pragma unroll
    for (int tj = 0; tj < 4; ++tj) {
        const int jg = jb + tj * 16;
        const int4v t4 = *(const int4v*)(tgt + jg);   // 4 consecutive j-targets
        #pragma unroll
        for (int tc = 0; tc < 4; ++tc) {
            const int tivc = tiv[tc];
            #pragma unroll
            for (int r = 0; r < 4; ++r) {
                float v = exp2f(fmaf(L2E10, acc[tj][tc][r], -L2E10));
                if (DIAG) {
                    if (jg + r == ic[tc]) v = 0.f;    // exclude diagonal
                }
                ts[tc] += v;
                ps[tc] += (t4[r] == tivc) ? v : 0.f;
            }
        }
    }
}

__global__ __launch_bounds__(256, 3) void tile_kernel(const uint8_t* __restrict__ e8,
                                                      const int* __restrict__ tgt,
                                                      float* __restrict__ pps,
                                                      float* __restrict__ pts)
{
    __shared__ uint8_t sA[BJ * KCB];   // 16 KB (j rows, one 128B k-chunk, xor-swizzled 16B units)
    __shared__ uint8_t sB[BI * KCB];   // 16 KB (i rows)

    const int bi   = blockIdx.x;
    const int bj   = blockIdx.y;
    const int tid  = threadIdx.x;
    const int wave = tid >> 6;
    const int lane = tid & 63;
    const int quad = lane >> 4;
    const int m    = lane & 15;

    const int wr = (wave >> 1) * 64;   // wave j base within block
    const int wc = (wave & 1) * 64;    // wave i base within block

    floatx4 acc[4][4];
    #pragma unroll
    for (int a = 0; a < 4; ++a)
        #pragma unroll
        for (int b = 0; b < 4; ++b)
            acc[a][b] = (floatx4){0.f, 0.f, 0.f, 0.f};

    // staging: 16B slot s -> row = s>>3, phys chunk = s&7, logical lc = (s&7)^(row&7)
    // (identical slot->offset map for A and B: each wave stages 256 slots = 32 rows)
    int goff[4];
    #pragma unroll
    for (int t = 0; t < 4; ++t) {
        int s   = wave * 256 + t * 64 + lane;
        int row = s >> 3;
        int lc  = (s & 7) ^ (row & 7);
        goff[t] = row * 256 + lc * 16;
    }

    const char* gA = (const char*)(e8 + (size_t)bj * BJ * 256);  // j rows
    const char* gB = (const char*)(e8 + (size_t)bi * BI * 256);  // i rows

    // fragment read: row&7 == m&7 -> xor is tile-independent
    const int xr = m & 7;
    const int c0 = (((quad << 1)    ) ^ xr) << 4;   // phys byte off of logical chunk 2q
    const int c1 = (((quad << 1) | 1) ^ xr) << 4;   // logical chunk 2q+1

    #pragma unroll
    for (int kc = 0; kc < NKC; ++kc) {
        #pragma unroll
        for (int t = 0; t < 4; ++t)
            gload_lds16(gA + goff[t] + kc * KCB, sA + wave * 4096 + t * 1024);
        #pragma unroll
        for (int t = 0; t < 4; ++t)
            gload_lds16(gB + goff[t] + kc * KCB, sB + wave * 4096 + t * 1024);
        __syncthreads();   // drains vmcnt -> staged data visible

        int8v bfr[4];
        #pragma unroll
        for (int tc = 0; tc < 4; ++tc) {
            const uint8_t* pb = sB + (wc + tc * 16 + m) * KCB;
            int4v lo = *(const int4v*)(pb + c0);
            int4v hi = *(const int4v*)(pb + c1);
            bfr[tc] = __builtin_shufflevector(lo, hi, 0, 1, 2, 3, 4, 5, 6, 7);
        }
        #pragma unroll
        for (int tj = 0; tj < 4; ++tj) {
            const uint8_t* pa = sA + (wr + tj * 16 + m) * KCB;
            int4v lo = *(const int4v*)(pa + c0);
            int4v hi = *(const int4v*)(pa + c1);
            int8v af = __builtin_shufflevector(lo, hi, 0, 1, 2, 3, 4, 5, 6, 7);
            #pragma unroll
            for (int tc = 0; tc < 4; ++tc)
                acc[tj][tc] = __builtin_amdgcn_mfma_scale_f32_16x16x128_f8f6f4(
                    af, bfr[tc], acc[tj][tc], 0, 0,
                    0, SCALE_1_16, 0, SCALE_1_16);
        }
        __syncthreads();   // reads done before restage
    }

    // ---- epilogue: exp(sim-10); total + positive sums per fixed i ----
    int tiv[4], ic[4];
    #pragma unroll
    for (int tc = 0; tc < 4; ++tc) {
        ic[tc]  = bi * BI + wc + tc * 16 + m;
        tiv[tc] = tgt[ic[tc]];
    }

    float ps[4] = {0.f, 0.f, 0.f, 0.f};
    float ts[4] = {0.f, 0.f, 0.f, 0.f};

    const int jb = bj * BJ + wr + (quad << 2);
    if (bi == bj)   // block-uniform: only 64/4096 blocks touch the diagonal
        epilogue_accum<true >(acc, tgt, jb, tiv, ic, ps, ts);
    else
        epilogue_accum<false>(acc, tgt, jb, tiv, ic, ps, ts);

    // quad-reduction: lanes m, m+16, m+32, m+48 hold disjoint j's for the same i
    #pragma unroll
    for (int tc = 0; tc < 4; ++tc) {
        ps[tc] += __shfl_xor(ps[tc], 16, 64);
        ps[tc] += __shfl_xor(ps[tc], 32, 64);
        ts[tc] += __shfl_xor(ts[tc], 16, 64);
        ts[tc] += __shfl_xor(ts[tc], 32, 64);
    }
    if (quad == 0) {
        const size_t base = (size_t)(bj * 2 + (wave >> 1)) * NROWS;
        #pragma unroll
        for (int tc = 0; tc < 4; ++tc) {
            pps[base + ic[tc]] = ps[tc];
            pts[base + ic[tc]] = ts[tc];
        }
    }
}

// ------------- Kernel 3: per-row log-diff + global sum -------------
__global__ __launch_bounds__(256) void finalize_kernel(const float* __restrict__ pps,
                                                       const float* __restrict__ pts,
                                                       float* __restrict__ out)
{
    const int i = blockIdx.x * 256 + threadIdx.x;
    float sp = 0.f, st = 0.f;
    #pragma unroll 8
    for (int t = 0; t < NPART; ++t) {
        sp += pps[(size_t)t * NROWS + i];
        st += pts[(size_t)t * NROWS + i];
    }
    float ns = st - sp;                 // negatives = total - positives (diag excluded in both)
    float loss = logf(ns) - logf(sp);   // fixed +10 shifts cancel
    #pragma unroll
    for (int off = 32; off > 0; off >>= 1)
        loss += __shfl_xor(loss, off, 64);
    __shared__ float w4[4];
    if ((threadIdx.x & 63) == 0) w4[threadIdx.x >> 6] = loss;
    __syncthreads();
    if (threadIdx.x == 0)
        atomicAdd(out, w4[0] + w4[1] + w4[2] + w4[3]);
}

extern "C" void kernel_launch(void* const* d_in, const int* in_sizes, int n_in,
                              void* d_out, int out_size, void* d_ws, size_t ws_size,
                              hipStream_t stream)
{
    (void)in_sizes; (void)n_in; (void)out_size; (void)ws_size;
    const float* emb = (const float*)d_in[0];
    const int*   tgt = (const int*)d_in[1];
    float*       out = (float*)d_out;

    uint32_t* e8  = (uint32_t*)d_ws;                                  // 2 MB fp8 rows
    float*    pps = (float*)((char*)d_ws + (size_t)NROWS * 256);      // 4 MB
    float*    pts = pps + (size_t)NPART * NROWS;                      // 4 MB

    normalize_kernel<<<NROWS / 4, 256, 0, stream>>>(emb, e8, out);

    dim3 grid(NIT, NJT);
    tile_kernel<<<grid, 256, 0, stream>>>((const uint8_t*)e8, tgt, pps, pts);

    finalize_kernel<<<NROWS / 256, 256, 0, stream>>>(pps, pts, out);
}

// Round 6
// 103.209 us; speedup vs baseline: 1.2613x; 1.0452x over previous
//
#include <hip/hip_runtime.h>
#include <hip/hip_bf16.h>
#include <stdint.h>
#include <math.h>

#define NROWS 8192
#define DIM   256          // elements per row; fp8 -> 256 B per row
#define BJ    256          // j rows per block (A operand)
#define BI    128          // i rows per block (B operand)
#define KCB   128          // K-bytes staged per chunk
#define NKC   2            // 256 B / 128 B
#define NJT   (NROWS/BJ)   // 32
#define NIT   (NROWS/BI)   // 64
#define NPART (NJT*2)      // 64 partial rows (2 wave-rows per bj)

typedef __attribute__((ext_vector_type(4)))  int   int4v;
typedef __attribute__((ext_vector_type(8)))  int   int8v;
typedef __attribute__((ext_vector_type(16))) float floatx16;

typedef const __attribute__((address_space(1))) uint32_t gas_u32;
typedef __attribute__((address_space(3))) uint32_t las_u32;

#define SCALE_1_16 0x7B7B7B7B          // E8M0 123 = 2^-4 in every byte
#define L2E10      14.4269504088896f   // 10 * log2(e)

__device__ __forceinline__ void gload_lds16(const void* g, void* l) {
    // LDS dest = wave-uniform base + lane*16 ; global src per-lane
    __builtin_amdgcn_global_load_lds((gas_u32*)(uintptr_t)g,
                                     (las_u32*)(uintptr_t)l, 16, 0, 0);
}

// ------------- Kernel 1: row-normalize fp32 -> fp8 e4m3 (x16); also zero d_out -------------
__global__ __launch_bounds__(256) void normalize_kernel(const float* __restrict__ emb,
                                                        uint32_t* __restrict__ e8,
                                                        float* __restrict__ out)
{
    if (blockIdx.x == 0 && threadIdx.x == 0) *out = 0.f;   // replaces memset dispatch
    int row  = blockIdx.x * 4 + (threadIdx.x >> 6);
    int lane = threadIdx.x & 63;
    const float4* rowp = (const float4*)(emb + (size_t)row * DIM);
    float4 v = rowp[lane];
    float ss = v.x*v.x + v.y*v.y + v.z*v.z + v.w*v.w;
    #pragma unroll
    for (int off = 32; off > 0; off >>= 1)
        ss += __shfl_xor(ss, off, 64);
    // store e * 16 in e4m3; MFMA scales (2^-4 per operand) remove the 2^8
    float inv = 16.0f / fmaxf(sqrtf(ss), 1e-8f);
    int r = __builtin_amdgcn_cvt_pk_fp8_f32(v.x * inv, v.y * inv, 0, false);
    r     = __builtin_amdgcn_cvt_pk_fp8_f32(v.z * inv, v.w * inv, r, true);
    e8[(size_t)row * (DIM / 4) + lane] = (uint32_t)r;
}

// ------------- Kernel 2: 256j x 128i tile, MX-fp8 32x32x64 MFMA, LDS-staged -------------
// C[row=j][col=i] per 32x32 tile: col = lane&31, row = (reg&3) + 8*(reg>>2) + 4*(lane>>5).
// Wave tile: 128j x 64i = 4 jt x 2 it tiles, acc 8 x 16 = 128 regs/lane.
template<bool DIAG>
__device__ __forceinline__ void epilogue_accum(const floatx16 acc[4][2],
                                               const int* __restrict__ tgt,
                                               int jb0, const int tiv[2], const int ic[2],
                                               float ps[2], float ts[2])
{
    #pragma unroll
    for (int jt = 0; jt < 4; ++jt) {
        #pragma unroll
        for (int rq = 0; rq < 4; ++rq) {
            const int jg = jb0 + jt * 32 + rq * 8;      // + r2 (0..3)
            const int4v t4 = *(const int4v*)(tgt + jg); // 4 consecutive j-targets
            #pragma unroll
            for (int it = 0; it < 2; ++it) {
                const int tivc = tiv[it];
                #pragma unroll
                for (int r2 = 0; r2 < 4; ++r2) {
                    float v = exp2f(fmaf(L2E10, acc[jt][it][rq * 4 + r2], -L2E10));
                    if (DIAG) {
                        if (jg + r2 == ic[it]) v = 0.f; // exclude diagonal
                    }
                    ts[it] += v;
                    ps[it] += (t4[r2] == tivc) ? v : 0.f;
                }
            }
        }
    }
}

__global__ __launch_bounds__(256, 2) void tile_kernel(const uint8_t* __restrict__ e8,
                                                      const int* __restrict__ tgt,
                                                      float* __restrict__ pps,
                                                      float* __restrict__ pts)
{
    __shared__ uint8_t sA[BJ * KCB];   // 32 KB (j rows, one 128B k-chunk, xor-swizzled 16B units)
    __shared__ uint8_t sB[BI * KCB];   // 16 KB (i rows)

    const int bi   = blockIdx.x;
    const int bj   = blockIdx.y;
    const int tid  = threadIdx.x;
    const int wave = tid >> 6;
    const int lane = tid & 63;
    const int col  = lane & 31;        // MFMA row/col index within 32
    const int h    = lane >> 5;        // K-half select

    const int wr = (wave >> 1) * 128;  // wave j base within block
    const int wc = (wave & 1) * 64;    // wave i base within block

    floatx16 acc[4][2];
    #pragma unroll
    for (int a = 0; a < 4; ++a)
        #pragma unroll
        for (int b = 0; b < 2; ++b)
            acc[a][b] = (floatx16){0.f,0.f,0.f,0.f,0.f,0.f,0.f,0.f,
                                   0.f,0.f,0.f,0.f,0.f,0.f,0.f,0.f};

    // staging: 16B slot s -> row = s>>3, phys chunk = s&7, logical lc = (s&7)^(row&7)
    int goffA[8];
    #pragma unroll
    for (int t = 0; t < 8; ++t) {
        int s   = wave * 512 + t * 64 + lane;
        int row = s >> 3;
        int lc  = (s & 7) ^ (row & 7);
        goffA[t] = row * 256 + lc * 16;
    }
    int goffB[4];
    #pragma unroll
    for (int t = 0; t < 4; ++t) {
        int s   = wave * 256 + t * 64 + lane;
        int row = s >> 3;
        int lc  = (s & 7) ^ (row & 7);
        goffB[t] = row * 256 + lc * 16;
    }

    const char* gA = (const char*)(e8 + (size_t)bj * BJ * 256);  // j rows
    const char* gB = (const char*)(e8 + (size_t)bi * BI * 256);  // i rows

    // fragment read: lane needs row (base + col), k-bytes [s*64 + h*32, +32)
    // logical chunks {4s+2h, 4s+2h+1}; phys = logical ^ (row&7); row&7 == lane&7
    const int xr = lane & 7;
    int coff[2][2];   // [s][c] phys byte offsets
    #pragma unroll
    for (int s = 0; s < 2; ++s)
        #pragma unroll
        for (int c = 0; c < 2; ++c)
            coff[s][c] = ((s * 4 + h * 2 + c) ^ xr) << 4;

    #pragma unroll
    for (int kc = 0; kc < NKC; ++kc) {
        #pragma unroll
        for (int t = 0; t < 8; ++t)
            gload_lds16(gA + goffA[t] + kc * KCB, sA + wave * 8192 + t * 1024);
        #pragma unroll
        for (int t = 0; t < 4; ++t)
            gload_lds16(gB + goffB[t] + kc * KCB, sB + wave * 4096 + t * 1024);
        __syncthreads();   // drains vmcnt -> staged data visible

        int8v bfr[2][2];   // [s][it]
        #pragma unroll
        for (int it = 0; it < 2; ++it) {
            const uint8_t* pb = sB + (wc + it * 32 + col) * KCB;
            #pragma unroll
            for (int s = 0; s < 2; ++s) {
                int4v lo = *(const int4v*)(pb + coff[s][0]);
                int4v hi = *(const int4v*)(pb + coff[s][1]);
                bfr[s][it] = __builtin_shufflevector(lo, hi, 0, 1, 2, 3, 4, 5, 6, 7);
            }
        }
        #pragma unroll
        for (int jt = 0; jt < 4; ++jt) {
            const uint8_t* pa = sA + (wr + jt * 32 + col) * KCB;
            #pragma unroll
            for (int s = 0; s < 2; ++s) {
                int4v lo = *(const int4v*)(pa + coff[s][0]);
                int4v hi = *(const int4v*)(pa + coff[s][1]);
                int8v af = __builtin_shufflevector(lo, hi, 0, 1, 2, 3, 4, 5, 6, 7);
                #pragma unroll
                for (int it = 0; it < 2; ++it)
                    acc[jt][it] = __builtin_amdgcn_mfma_scale_f32_32x32x64_f8f6f4(
                        af, bfr[s][it], acc[jt][it], 0, 0,
                        0, SCALE_1_16, 0, SCALE_1_16);
            }
        }
        __syncthreads();   // reads done before restage
    }

    // ---- epilogue: exp(sim-10); total + positive sums per fixed i ----
    int tiv[2], ic[2];
    #pragma unroll
    for (int it = 0; it < 2; ++it) {
        ic[it]  = bi * BI + wc + it * 32 + col;
        tiv[it] = tgt[ic[it]];
    }

    float ps[2] = {0.f, 0.f};
    float ts[2] = {0.f, 0.f};

    const int jb0 = bj * BJ + wr + h * 4;
    if ((bi >> 1) == bj)   // block-uniform: only 64/2048 blocks touch the diagonal
        epilogue_accum<true >(acc, tgt, jb0, tiv, ic, ps, ts);
    else
        epilogue_accum<false>(acc, tgt, jb0, tiv, ic, ps, ts);

    // reduce over the K-half bit: lanes L and L+32 hold same i, disjoint j's
    #pragma unroll
    for (int it = 0; it < 2; ++it) {
        ps[it] += __shfl_xor(ps[it], 32, 64);
        ts[it] += __shfl_xor(ts[it], 32, 64);
    }
    if (h == 0) {
        const size_t base = (size_t)(bj * 2 + (wave >> 1)) * NROWS;
        #pragma unroll
        for (int it = 0; it < 2; ++it) {
            pps[base + ic[it]] = ps[it];
            pts[base + ic[it]] = ts[it];
        }
    }
}

// ------------- Kernel 3: per-row log-diff + global sum -------------
__global__ __launch_bounds__(256) void finalize_kernel(const float* __restrict__ pps,
                                                       const float* __restrict__ pts,
                                                       float* __restrict__ out)
{
    const int i = blockIdx.x * 256 + threadIdx.x;
    float sp = 0.f, st = 0.f;
    #pragma unroll 8
    for (int t = 0; t < NPART; ++t) {
        sp += pps[(size_t)t * NROWS + i];
        st += pts[(size_t)t * NROWS + i];
    }
    float ns = st - sp;                 // negatives = total - positives (diag excluded in both)
    float loss = logf(ns) - logf(sp);   // fixed +10 shifts cancel
    #pragma unroll
    for (int off = 32; off > 0; off >>= 1)
        loss += __shfl_xor(loss, off, 64);
    __shared__ float w4[4];
    if ((threadIdx.x & 63) == 0) w4[threadIdx.x >> 6] = loss;
    __syncthreads();
    if (threadIdx.x == 0)
        atomicAdd(out, w4[0] + w4[1] + w4[2] + w4[3]);
}

extern "C" void kernel_launch(void* const* d_in, const int* in_sizes, int n_in,
                              void* d_out, int out_size, void* d_ws, size_t ws_size,
                              hipStream_t stream)
{
    (void)in_sizes; (void)n_in; (void)out_size; (void)ws_size;
    const float* emb = (const float*)d_in[0];
    const int*   tgt = (const int*)d_in[1];
    float*       out = (float*)d_out;

    uint32_t* e8  = (uint32_t*)d_ws;                                  // 2 MB fp8 rows
    float*    pps = (float*)((char*)d_ws + (size_t)NROWS * 256);      // 2 MB
    float*    pts = pps + (size_t)NPART * NROWS;                      // 2 MB

    normalize_kernel<<<NROWS / 4, 256, 0, stream>>>(emb, e8, out);

    dim3 grid(NIT, NJT);
    tile_kernel<<<grid, 256, 0, stream>>>((const uint8_t*)e8, tgt, pps, pts);

    finalize_kernel<<<NROWS / 256, 256, 0, stream>>>(pps, pts, out);
}

// Round 7
// 97.998 us; speedup vs baseline: 1.3283x; 1.0532x over previous
//
#include <hip/hip_runtime.h>
#include <hip/hip_bf16.h>
#include <stdint.h>
#include <math.h>

#define NROWS 8192
#define DIM   256          // elements per row; fp8 -> 256 B per row
#define RB    256          // row bytes (fp8)
#define BI    128          // i rows per block (B operand, register-resident frags)
#define JBLK  512          // j rows per block (A operand, streamed)
#define NBJS  4            // sub-tiles of 128 j
#define NG    (NROWS/JBLK) // 16 j-groups
#define NIT   (NROWS/BI)   // 64 i-tiles

typedef __attribute__((ext_vector_type(4)))  int   int4v;
typedef __attribute__((ext_vector_type(8)))  int   int8v;
typedef __attribute__((ext_vector_type(16))) float floatx16;

typedef const __attribute__((address_space(1))) uint32_t gas_u32;
typedef __attribute__((address_space(3))) uint32_t las_u32;

#define SCALE_1_16 0x7B7B7B7B          // E8M0 123 = 2^-4 in every byte
#define L2E10      14.4269504088896f   // 10 * log2(e)

__device__ __forceinline__ void gload_lds16(const void* g, void* l) {
    // LDS dest = wave-uniform base + lane*16 ; global src per-lane
    __builtin_amdgcn_global_load_lds((gas_u32*)(uintptr_t)g,
                                     (las_u32*)(uintptr_t)l, 16, 0, 0);
}

// ------------- Kernel 1: row-normalize fp32 -> fp8 e4m3 (x16); also zero d_out -------------
__global__ __launch_bounds__(256) void normalize_kernel(const float* __restrict__ emb,
                                                        uint32_t* __restrict__ e8,
                                                        float* __restrict__ out)
{
    if (blockIdx.x == 0 && threadIdx.x == 0) *out = 0.f;   // replaces memset dispatch
    int row  = blockIdx.x * 4 + (threadIdx.x >> 6);
    int lane = threadIdx.x & 63;
    const float4* rowp = (const float4*)(emb + (size_t)row * DIM);
    float4 v = rowp[lane];
    float ss = v.x*v.x + v.y*v.y + v.z*v.z + v.w*v.w;
    #pragma unroll
    for (int off = 32; off > 0; off >>= 1)
        ss += __shfl_xor(ss, off, 64);
    // store e * 16 in e4m3; MFMA scales (2^-4 per operand) remove the 2^8
    float inv = 16.0f / fmaxf(sqrtf(ss), 1e-8f);
    int r = __builtin_amdgcn_cvt_pk_fp8_f32(v.x * inv, v.y * inv, 0, false);
    r     = __builtin_amdgcn_cvt_pk_fp8_f32(v.z * inv, v.w * inv, r, true);
    e8[(size_t)row * (DIM / 4) + lane] = (uint32_t)r;
}

// ------------- Kernel 2: B-resident, A-streamed MX-fp8 32x32x64, overlapped staging -------
// Wave tile per sub-tile: 64j x 64i (2jt x 2it), acc = 64 regs; B frags = 64 regs.
template<bool DIAG>
__device__ __forceinline__ void epi(const floatx16 acc[2][2],
                                    const int* __restrict__ tgt,
                                    int jb, const int tiv[2], const int ic[2],
                                    float ps[2], float ts[2])
{
    #pragma unroll
    for (int jt = 0; jt < 2; ++jt) {
        #pragma unroll
        for (int rq = 0; rq < 4; ++rq) {
            const int jg_ = jb + jt * 32 + rq * 8;       // + r2 (0..3)
            const int4v t4 = *(const int4v*)(tgt + jg_); // 4 consecutive j-targets
            #pragma unroll
            for (int it = 0; it < 2; ++it) {
                const int tivc = tiv[it];
                #pragma unroll
                for (int r2 = 0; r2 < 4; ++r2) {
                    float v = exp2f(fmaf(L2E10, acc[jt][it][rq * 4 + r2], -L2E10));
                    if (DIAG) {
                        if (jg_ + r2 == ic[it]) v = 0.f; // exclude diagonal
                    }
                    ts[it] += v;
                    ps[it] += (t4[r2] == tivc) ? v : 0.f;
                }
            }
        }
    }
}

__global__ __launch_bounds__(256, 2) void tile_kernel(const uint8_t* __restrict__ e8,
                                                      const int* __restrict__ tgt,
                                                      float* __restrict__ pps,
                                                      float* __restrict__ pts)
{
    __shared__ uint8_t buf[2][BI * RB];   // 2 x 32 KB: A double-buffer; buf[1] boots as B

    const int bi   = blockIdx.x;
    const int jg   = blockIdx.y;
    const int tid  = threadIdx.x;
    const int wave = tid >> 6;
    const int lane = tid & 63;
    const int col  = lane & 31;        // MFMA row/col within 32
    const int h    = lane >> 5;        // K-half select

    const int wr = (wave >> 1) * 64;   // wave j base within 128-row sub-tile
    const int wc = (wave & 1) * 64;    // wave i base within 128

    // staging map (mod-16 xor swizzle, 256-B rows): slot s -> row=s>>4,
    // phys chunk = s&15, logical lc = (s&15)^(row&15)
    int goff[8];
    #pragma unroll
    for (int t = 0; t < 8; ++t) {
        int s   = wave * 512 + t * 64 + lane;
        int row = s >> 4;
        int lc  = (s & 15) ^ (row & 15);
        goff[t] = row * RB + lc * 16;
    }

    const char* gB = (const char*)(e8 + (size_t)bi * BI * RB);   // i rows
    const char* gA = (const char*)(e8 + (size_t)jg * JBLK * RB); // j rows (4 sub-tiles)

    // boot: stage A sub-tile 0 -> buf[0], B -> buf[1]
    #pragma unroll
    for (int t = 0; t < 8; ++t)
        gload_lds16(gA + goff[t], buf[0] + wave * 8192 + t * 1024);
    #pragma unroll
    for (int t = 0; t < 8; ++t)
        gload_lds16(gB + goff[t], buf[1] + wave * 8192 + t * 1024);
    __syncthreads();   // compiler drains vmcnt -> both staged

    // fragment phys-chunk offsets: logical chunks {s*4+h*2, +1}, xor (row&15)=(col&15)
    const int xm = col & 15;
    int poff[4][2];
    #pragma unroll
    for (int s = 0; s < 4; ++s)
        #pragma unroll
        for (int c = 0; c < 2; ++c)
            poff[s][c] = ((s * 4 + h * 2 + c) ^ xm) << 4;

    // B fragments -> registers (64 VGPRs), held for the whole kernel
    int8v bfr[2][4];
    #pragma unroll
    for (int it = 0; it < 2; ++it) {
        const uint8_t* pb = buf[1] + (wc + it * 32 + col) * RB;
        #pragma unroll
        for (int s = 0; s < 4; ++s) {
            int4v lo = *(const int4v*)(pb + poff[s][0]);
            int4v hi = *(const int4v*)(pb + poff[s][1]);
            bfr[it][s] = __builtin_shufflevector(lo, hi, 0, 1, 2, 3, 4, 5, 6, 7);
        }
    }
    __syncthreads();   // all B reads done before sub-tile 0 restages buf[1]

    int tiv[2], ic[2];
    #pragma unroll
    for (int it = 0; it < 2; ++it) {
        ic[it]  = bi * BI + wc + it * 32 + col;
        tiv[it] = tgt[ic[it]];
    }

    float ps[2] = {0.f, 0.f};
    float ts[2] = {0.f, 0.f};

    const int dbi = bi - jg * 4;   // sub-tile index that touches the diagonal (if 0..3)

    for (int bjs = 0; bjs < NBJS; ++bjs) {
        // issue next A stage (lands in the other buffer; drains at the barrier below,
        // i.e. AFTER this sub-tile's MFMAs + epilogue -> fully overlapped)
        if (bjs < NBJS - 1) {
            const char* gAn = gA + (size_t)(bjs + 1) * BI * RB;
            #pragma unroll
            for (int t = 0; t < 8; ++t)
                gload_lds16(gAn + goff[t], buf[(bjs + 1) & 1] + wave * 8192 + t * 1024);
        }

        const uint8_t* ab = buf[bjs & 1];
        floatx16 acc[2][2];
        #pragma unroll
        for (int a = 0; a < 2; ++a)
            #pragma unroll
            for (int b = 0; b < 2; ++b)
                acc[a][b] = (floatx16){0.f,0.f,0.f,0.f,0.f,0.f,0.f,0.f,
                                       0.f,0.f,0.f,0.f,0.f,0.f,0.f,0.f};

        #pragma unroll
        for (int s = 0; s < 4; ++s) {
            int8v af[2];
            #pragma unroll
            for (int jt = 0; jt < 2; ++jt) {
                const uint8_t* pa = ab + (wr + jt * 32 + col) * RB;
                int4v lo = *(const int4v*)(pa + poff[s][0]);
                int4v hi = *(const int4v*)(pa + poff[s][1]);
                af[jt] = __builtin_shufflevector(lo, hi, 0, 1, 2, 3, 4, 5, 6, 7);
            }
            #pragma unroll
            for (int jt = 0; jt < 2; ++jt)
                #pragma unroll
                for (int it = 0; it < 2; ++it)
                    acc[jt][it] = __builtin_amdgcn_mfma_scale_f32_32x32x64_f8f6f4(
                        af[jt], bfr[it][s], acc[jt][it], 0, 0,
                        0, SCALE_1_16, 0, SCALE_1_16);
        }

        // fused epilogue for this sub-tile (regs only + broadcast tgt loads)
        const int jb = jg * JBLK + bjs * BI + wr + h * 4;
        if (bjs == dbi)
            epi<true >(acc, tgt, jb, tiv, ic, ps, ts);
        else
            epi<false>(acc, tgt, jb, tiv, ic, ps, ts);

        if (bjs < NBJS - 1)
            __syncthreads();   // single barrier per sub-tile: drains next-A DMA,
                               // guards restage of the buffer just read
    }

    // reduce over the K-half bit: lanes L and L+32 hold same i, disjoint j's
    #pragma unroll
    for (int it = 0; it < 2; ++it) {
        ps[it] += __shfl_xor(ps[it], 32, 64);
        ts[it] += __shfl_xor(ts[it], 32, 64);
    }
    if (h == 0) {
        const size_t base = (size_t)jg * NROWS;
        #pragma unroll
        for (int it = 0; it < 2; ++it) {
            pps[base + ic[it]] = ps[it];
            pts[base + ic[it]] = ts[it];
        }
    }
}

// ------------- Kernel 3: per-row log-diff + global sum -------------
__global__ __launch_bounds__(256) void finalize_kernel(const float* __restrict__ pps,
                                                       const float* __restrict__ pts,
                                                       float* __restrict__ out)
{
    const int i = blockIdx.x * 256 + threadIdx.x;
    float sp = 0.f, st = 0.f;
    #pragma unroll
    for (int t = 0; t < NG; ++t) {
        sp += pps[(size_t)t * NROWS + i];
        st += pts[(size_t)t * NROWS + i];
    }
    float ns = st - sp;                 // negatives = total - positives (diag excluded in both)
    float loss = logf(ns) - logf(sp);   // fixed +10 shifts cancel
    #pragma unroll
    for (int off = 32; off > 0; off >>= 1)
        loss += __shfl_xor(loss, off, 64);
    __shared__ float w4[4];
    if ((threadIdx.x & 63) == 0) w4[threadIdx.x >> 6] = loss;
    __syncthreads();
    if (threadIdx.x == 0)
        atomicAdd(out, w4[0] + w4[1] + w4[2] + w4[3]);
}

extern "C" void kernel_launch(void* const* d_in, const int* in_sizes, int n_in,
                              void* d_out, int out_size, void* d_ws, size_t ws_size,
                              hipStream_t stream)
{
    (void)in_sizes; (void)n_in; (void)out_size; (void)ws_size;
    const float* emb = (const float*)d_in[0];
    const int*   tgt = (const int*)d_in[1];
    float*       out = (float*)d_out;

    uint32_t* e8  = (uint32_t*)d_ws;                                  // 2 MB fp8 rows
    float*    pps = (float*)((char*)d_ws + (size_t)NROWS * RB);       // 512 KB
    float*    pts = pps + (size_t)NG * NROWS;                         // 512 KB

    normalize_kernel<<<NROWS / 4, 256, 0, stream>>>(emb, e8, out);

    dim3 grid(NIT, NG);
    tile_kernel<<<grid, 256, 0, stream>>>((const uint8_t*)e8, tgt, pps, pts);

    finalize_kernel<<<NROWS / 256, 256, 0, stream>>>(pps, pts, out);
}